// Round 8
// baseline (129.750 us; speedup 1.0000x reference)
//
#include <hip/hip_runtime.h>
#include <hip/hip_bf16.h>
#include <math.h>

#define BATCH 2048
#define LATENT 64
#define LOG_2PI 1.8378770664093453f
#define BETA_M1 5.0f
#define LN2 0.69314718055994530942f
// C2 = -0.5 * log2(e)
#define C2 (-0.72134752044448170368f)
#define EXP2F __builtin_amdgcn_exp2f
#define LOG2F __builtin_amdgcn_logf

// packed fp32 fma: d.{x,y} = a.{x,y}*b.{x,y} + c.{x,y}  (one VOP3P inst)
__device__ __forceinline__ float2 pk_fma(float2 a, float2 b, float2 c) {
    float2 d;
    asm("v_pk_fma_f32 %0, %1, %2, %3" : "=v"(d) : "v"(a), "v"(b), "v"(c));
    return d;
}

// ws layout (float offsets):
//   Vt   [128][2048]  Vt[2l][j]=C2*inv, Vt[2l+1][j]=C2*m*inv
//   Tce  [64][2048]   Tce[l][j]=C2*(m^2*inv+lv+LOG2PI)
//   Up   [128][2048]  Up[2l][i]=z^2, Up[2l+1][i]=-2z
//   CE   [2048], KLP [2048]
//   RMP/RSP [2][2048] row-LSE partials (log2 domain)
//   PART [16]         PART[0]=tc, PART[1]=kl, PART[2]=ticket
//   PP   bf16 [16][64][2048] per-j-chunk raw exp sums (4 MB)
#define OFF_VT   0
#define OFF_TCE  (128*BATCH)
#define OFF_UP   (OFF_TCE + 64*BATCH)
#define OFF_CE   (OFF_UP + 128*BATCH)
#define OFF_KLP  (OFF_CE + BATCH)
#define OFF_RMP  (OFF_KLP + BATCH)
#define OFF_RSP  (OFF_RMP + 2*BATCH)
#define OFF_PART (OFF_RSP + 2*BATCH)
#define OFF_PP   (OFF_PART + 16)

// Precompute: grid 128 x 256, each block transposes 16 j x 64 l. (R0-proven.)
__global__ __launch_bounds__(256) void precompute_kernel(const float* __restrict__ z,
                                                         const float* __restrict__ zm,
                                                         const float* __restrict__ zlv,
                                                         float* __restrict__ ws) {
    __shared__ float Tz[16][65], Tm[16][65], Tlv[16][65];
    __shared__ float CEp[16][16], KLp[16][16];
    int t = threadIdx.x, lane = t & 63, w = t >> 6;
    int j0 = blockIdx.x * 16;

    #pragma unroll
    for (int p = 0; p < 4; ++p) {
        int jr = p * 4 + w;
        int idx = (j0 + jr) * LATENT + lane;
        Tz[jr][lane]  = z[idx];
        Tm[jr][lane]  = zm[idx];
        Tlv[jr][lane] = zlv[idx];
    }
    if (blockIdx.x == 0 && t < 16) ws[OFF_PART + t] = 0.0f;
    __syncthreads();

    int jl = t & 15, lg = t >> 4;
    int j = j0 + jl;
    float ce_acc = 0.0f, kl_acc = 0.0f;
    #pragma unroll
    for (int q = 0; q < 4; ++q) {
        int l = q * 16 + lg;
        float zv = Tz[jl][l];
        float m  = Tm[jl][l];
        float lv = Tlv[jl][l];
        float iv  = __expf(-lv);
        float civ = C2 * iv;
        float miv = m * iv;
        float cmv = C2 * miv;
        float cev = C2 * fmaf(m, miv, lv + LOG_2PI);
        ws[OFF_VT  + (2*l)   * BATCH + j] = civ;
        ws[OFF_VT  + (2*l+1) * BATCH + j] = cmv;
        ws[OFF_TCE + l       * BATCH + j] = cev;
        ws[OFF_UP  + (2*l)   * BATCH + j] = zv * zv;
        ws[OFF_UP  + (2*l+1) * BATCH + j] = -2.0f * zv;
        ce_acc += cev;
        kl_acc += fmaf(m, m, __expf(lv)) - lv - 1.0f;
    }
    CEp[lg][jl] = ce_acc;
    KLp[lg][jl] = kl_acc;
    __syncthreads();
    if (t < 16) {
        float ce = 0.0f, kl = 0.0f;
        #pragma unroll
        for (int g = 0; g < 16; ++g) { ce += CEp[g][t]; kl += KLp[g][t]; }
        ws[OFF_CE  + j0 + t] = ce;
        ws[OFF_KLP + j0 + t] = kl;
    }
}

// Fused main: blocks [0,1024) dim path (8 i/thread, all 2048 i, 128-j chunk),
//             blocks [1024,1536) row path. 1536 blocks = 6/CU resident.
// Dim inner loop uses v_pk_fma_f32 on j-pairs: 2 FMA insts -> 1, cutting the
// VALU issue share (main is issue-rate-bound: R7's +50% waves changed nothing).
#define DIMB 1024
#define ROWB 512
__global__ __launch_bounds__(256) void main_kernel(float* __restrict__ ws) {
    __shared__ float RMs[8][4], RSs[8][4];
    int bx = blockIdx.x, t = threadIdx.x;

    if (bx < DIMB) {
        int l  = bx >> 4;
        int jc = bx & 15;

        const float* __restrict__ up0 = ws + OFF_UP + (2*l)   * BATCH;
        const float* __restrict__ up1 = ws + OFF_UP + (2*l+1) * BATCH;
        float2 z2b[8], n2b[8];
        #pragma unroll
        for (int k = 0; k < 8; ++k) {
            float a = up0[t + 256*k];
            float b = up1[t + 256*k];
            z2b[k] = make_float2(a, a);
            n2b[k] = make_float2(b, b);
        }

        const float2* __restrict__ pc2 = (const float2*)(ws + OFF_VT  + (2*l)   * BATCH + jc * 128);
        const float2* __restrict__ pm2 = (const float2*)(ws + OFF_VT  + (2*l+1) * BATCH + jc * 128);
        const float2* __restrict__ pe2 = (const float2*)(ws + OFF_TCE + l       * BATCH + jc * 128);

        float s[8];
        #pragma unroll
        for (int k = 0; k < 8; ++k) s[k] = 0.0f;

        for (int jj = 0; jj < 64; jj += 4) {   // 4 j-pairs = 8 j per iter
            #pragma unroll
            for (int u = 0; u < 4; ++u) {
                float2 cc = pc2[jj + u];   // uniform -> scalar load
                float2 mm = pm2[jj + u];   // uniform -> scalar load
                float2 ee = pe2[jj + u];   // uniform -> scalar load
                #pragma unroll
                for (int k = 0; k < 8; ++k) {
                    float2 t0 = pk_fma(n2b[k], mm, ee);
                    float2 t1 = pk_fma(z2b[k], cc, t0);
                    s[k] += EXP2F(t1.x);
                    s[k] += EXP2F(t1.y);
                }
            }
        }

        __hip_bfloat16* pp = (__hip_bfloat16*)(ws + OFF_PP);
        size_t base = ((size_t)(jc * 64 + l)) * BATCH;
        #pragma unroll
        for (int k = 0; k < 8; ++k)
            pp[base + t + 256*k] = __float2bfloat16(s[k]);
    } else {
        // row path: 8 i per block, 4 j per thread over a j-half (R0-proven)
        int bx2 = bx - DIMB;
        int ib8 = bx2 >> 1, ph = bx2 & 1;
        int i0 = ib8 * 8;
        int jb = ph * 1024 + 4 * t;
        int lane = t & 63, w = t >> 6;

        const float* __restrict__ Vt = ws + OFF_VT;
        const float* __restrict__ Up = ws + OFF_UP;

        float r[8][4];
        #pragma unroll
        for (int i = 0; i < 8; ++i)
            r[i][0] = r[i][1] = r[i][2] = r[i][3] = 0.0f;

        for (int l = 0; l < LATENT; ++l) {
            float4 v0 = *(const float4*)(Vt + (2*l)   * BATCH + jb);
            float4 v1 = *(const float4*)(Vt + (2*l+1) * BATCH + jb);
            const float* __restrict__ u0 = Up + (2*l)   * BATCH + i0;  // uniform -> s_load
            const float* __restrict__ u1 = Up + (2*l+1) * BATCH + i0;  // uniform -> s_load
            #pragma unroll
            for (int i = 0; i < 8; ++i) {
                float a = u0[i], b = u1[i];
                r[i][0] = fmaf(a, v0.x, fmaf(b, v1.x, r[i][0]));
                r[i][1] = fmaf(a, v0.y, fmaf(b, v1.y, r[i][1]));
                r[i][2] = fmaf(a, v0.z, fmaf(b, v1.z, r[i][2]));
                r[i][3] = fmaf(a, v0.w, fmaf(b, v1.w, r[i][3]));
            }
        }

        float4 ce4 = *(const float4*)(ws + OFF_CE + jb);
        #pragma unroll
        for (int i = 0; i < 8; ++i) {
            float rc0 = r[i][0] + ce4.x, rc1 = r[i][1] + ce4.y;
            float rc2 = r[i][2] + ce4.z, rc3 = r[i][3] + ce4.w;
            float M = fmaxf(fmaxf(rc0, rc1), fmaxf(rc2, rc3));
            float S = EXP2F(rc0 - M) + EXP2F(rc1 - M)
                    + EXP2F(rc2 - M) + EXP2F(rc3 - M);
            #pragma unroll
            for (int off = 32; off > 0; off >>= 1) {
                float Mo = __shfl_xor(M, off, 64);
                float So = __shfl_xor(S, off, 64);
                float mn = fmaxf(M, Mo);
                S = S * EXP2F(M - mn) + So * EXP2F(Mo - mn);
                M = mn;
            }
            if (lane == 0) { RMs[i][w] = M; RSs[i][w] = S; }
        }
        __syncthreads();
        if (t < 8) {
            float M = RMs[t][0], S = RSs[t][0];
            #pragma unroll
            for (int w2 = 1; w2 < 4; ++w2) {
                float Mo = RMs[t][w2], So = RSs[t][w2];
                float mn = fmaxf(M, Mo);
                S = S * EXP2F(M - mn) + So * EXP2F(Mo - mn);
                M = mn;
            }
            ws[OFF_RMP + ph * BATCH + i0 + t] = M;
            ws[OFF_RSP + ph * BATCH + i0 + t] = S;
        }
    }
}

// Finalize: tc = sum_i lqz_i - sum_{l,i} log2(sum_c PP[c][l][i]); kl from KLP.
// Grid 512 x 256 (R7 ran 128 blocks = half the CUs idle): 1 (l,i) per thread.
// Last block (atomic ticket) assembles the scalar output.
__global__ __launch_bounds__(256) void finalize_kernel(float* __restrict__ ws,
                                                       float* __restrict__ out) {
    __shared__ float s_tc[256];
    __shared__ float s_kl[256];
    int t = threadIdx.x;
    int gid = blockIdx.x * 256 + t;          // 0..131071

    const __hip_bfloat16* __restrict__ pp = (const __hip_bfloat16*)(ws + OFF_PP);

    float acc = 0.0f, kl = 0.0f;
    {
        int l = gid >> 11, i = gid & 2047;
        float s = 0.0f;
        #pragma unroll
        for (int c = 0; c < 16; ++c)
            s += __bfloat162float(pp[((size_t)(c * 64 + l)) * BATCH + i]);
        acc -= LOG2F(s);                  // log2 domain; LN2-scaled at the end
    }

    if (gid < BATCH) {
        int i = gid;
        float M0 = ws[OFF_RMP + i], M1 = ws[OFF_RMP + BATCH + i];
        float S0 = ws[OFF_RSP + i], S1 = ws[OFF_RSP + BATCH + i];
        float mn = fmaxf(M0, M1);
        acc += mn + LOG2F(S0 * EXP2F(M0 - mn) + S1 * EXP2F(M1 - mn));
        kl = ws[OFF_KLP + i];
    }

    s_tc[t] = acc; s_kl[t] = kl;
    __syncthreads();
    for (int s2 = 128; s2 > 0; s2 >>= 1) {
        if (t < s2) { s_tc[t] += s_tc[t + s2]; s_kl[t] += s_kl[t + s2]; }
        __syncthreads();
    }
    if (t == 0) {
        atomicAdd(&ws[OFF_PART + 0], s_tc[0]);
        atomicAdd(&ws[OFF_PART + 1], s_kl[0]);
        __threadfence();
        unsigned int old = atomicAdd((unsigned int*)(ws + OFF_PART + 2), 1u);
        if (old == 511u) {
            float tc  = atomicAdd(&ws[OFF_PART + 0], 0.0f);
            float kl2 = atomicAdd(&ws[OFF_PART + 1], 0.0f);
            out[0] = BETA_M1 * (LN2 * tc / (float)BATCH) + 0.5f * (kl2 / (float)BATCH);
        }
    }
}

extern "C" void kernel_launch(void* const* d_in, const int* in_sizes, int n_in,
                              void* d_out, int out_size, void* d_ws, size_t ws_size,
                              hipStream_t stream) {
    const float* z        = (const float*)d_in[0];
    const float* z_mean   = (const float*)d_in[1];
    const float* z_logvar = (const float*)d_in[2];
    float* out = (float*)d_out;
    float* ws  = (float*)d_ws;

    precompute_kernel<<<128, 256, 0, stream>>>(z, z_mean, z_logvar, ws);
    main_kernel<<<DIMB + ROWB, 256, 0, stream>>>(ws);
    finalize_kernel<<<512, 256, 0, stream>>>(ws, out);
}

// Round 9
// 127.701 us; speedup vs baseline: 1.0160x; 1.0160x over previous
//
#include <hip/hip_runtime.h>
#include <hip/hip_bf16.h>
#include <math.h>

#define BATCH 2048
#define LATENT 64
#define LOG_2PI 1.8378770664093453f
#define BETA_M1 5.0f
#define LN2 0.69314718055994530942f
// C2 = -0.5 * log2(e)
#define C2 (-0.72134752044448170368f)
#define EXP2F __builtin_amdgcn_exp2f
#define LOG2F __builtin_amdgcn_logf

// packed fp32 fma: d.{x,y} = a.{x,y}*b.{x,y} + c.{x,y}  (one VOP3P inst)
__device__ __forceinline__ float2 pk_fma(float2 a, float2 b, float2 c) {
    float2 d;
    asm("v_pk_fma_f32 %0, %1, %2, %3" : "=v"(d) : "v"(a), "v"(b), "v"(c));
    return d;
}

// ws layout (float offsets):
//   Vt   [128][2048]  Vt[2l][j]=C2*inv, Vt[2l+1][j]=C2*m*inv
//   Tce  [64][2048]   Tce[l][j]=C2*(m^2*inv+lv+LOG2PI)
//   Up   [128][2048]  Up[2l][i]=z^2, Up[2l+1][i]=-2z
//   CE   [2048], KLP [2048]
//   RMP/RSP [2][2048] row-LSE partials (log2 domain)
//   PART [16]         PART[0]=tc, PART[1]=kl, PART[2]=ticket
//   PP   bf16 [16][64][2048] per-j-chunk raw exp sums (4 MB)
#define OFF_VT   0
#define OFF_TCE  (128*BATCH)
#define OFF_UP   (OFF_TCE + 64*BATCH)
#define OFF_CE   (OFF_UP + 128*BATCH)
#define OFF_KLP  (OFF_CE + BATCH)
#define OFF_RMP  (OFF_KLP + BATCH)
#define OFF_RSP  (OFF_RMP + 2*BATCH)
#define OFF_PART (OFF_RSP + 2*BATCH)
#define OFF_PP   (OFF_PART + 16)

// Precompute: grid 128 x 256, each block transposes 16 j x 64 l. (R0-proven.)
__global__ __launch_bounds__(256) void precompute_kernel(const float* __restrict__ z,
                                                         const float* __restrict__ zm,
                                                         const float* __restrict__ zlv,
                                                         float* __restrict__ ws) {
    __shared__ float Tz[16][65], Tm[16][65], Tlv[16][65];
    __shared__ float CEp[16][16], KLp[16][16];
    int t = threadIdx.x, lane = t & 63, w = t >> 6;
    int j0 = blockIdx.x * 16;

    #pragma unroll
    for (int p = 0; p < 4; ++p) {
        int jr = p * 4 + w;
        int idx = (j0 + jr) * LATENT + lane;
        Tz[jr][lane]  = z[idx];
        Tm[jr][lane]  = zm[idx];
        Tlv[jr][lane] = zlv[idx];
    }
    if (blockIdx.x == 0 && t < 16) ws[OFF_PART + t] = 0.0f;
    __syncthreads();

    int jl = t & 15, lg = t >> 4;
    int j = j0 + jl;
    float ce_acc = 0.0f, kl_acc = 0.0f;
    #pragma unroll
    for (int q = 0; q < 4; ++q) {
        int l = q * 16 + lg;
        float zv = Tz[jl][l];
        float m  = Tm[jl][l];
        float lv = Tlv[jl][l];
        float iv  = __expf(-lv);
        float civ = C2 * iv;
        float miv = m * iv;
        float cmv = C2 * miv;
        float cev = C2 * fmaf(m, miv, lv + LOG_2PI);
        ws[OFF_VT  + (2*l)   * BATCH + j] = civ;
        ws[OFF_VT  + (2*l+1) * BATCH + j] = cmv;
        ws[OFF_TCE + l       * BATCH + j] = cev;
        ws[OFF_UP  + (2*l)   * BATCH + j] = zv * zv;
        ws[OFF_UP  + (2*l+1) * BATCH + j] = -2.0f * zv;
        ce_acc += cev;
        kl_acc += fmaf(m, m, __expf(lv)) - lv - 1.0f;
    }
    CEp[lg][jl] = ce_acc;
    KLp[lg][jl] = kl_acc;
    __syncthreads();
    if (t < 16) {
        float ce = 0.0f, kl = 0.0f;
        #pragma unroll
        for (int g = 0; g < 16; ++g) { ce += CEp[g][t]; kl += KLp[g][t]; }
        ws[OFF_CE  + j0 + t] = ce;
        ws[OFF_KLP + j0 + t] = kl;
    }
}

// Fused main: blocks [0,1024) dim path (8 i/thread, all 2048 i, 128-j chunk),
//             blocks [1024,1536) row path. 1536 blocks = 6/CU resident.
// Both paths use v_pk_fma_f32: dim packs over j-pairs, row packs over i-pairs
// (main is issue-rate-bound: R7 +50% waves = no change; R8 pk_fma = -6.4 us).
#define DIMB 1024
#define ROWB 512
__global__ __launch_bounds__(256) void main_kernel(float* __restrict__ ws) {
    __shared__ float RMs[8][4], RSs[8][4];
    int bx = blockIdx.x, t = threadIdx.x;

    if (bx < DIMB) {
        int l  = bx >> 4;
        int jc = bx & 15;

        const float* __restrict__ up0 = ws + OFF_UP + (2*l)   * BATCH;
        const float* __restrict__ up1 = ws + OFF_UP + (2*l+1) * BATCH;
        float2 z2b[8], n2b[8];
        #pragma unroll
        for (int k = 0; k < 8; ++k) {
            float a = up0[t + 256*k];
            float b = up1[t + 256*k];
            z2b[k] = make_float2(a, a);
            n2b[k] = make_float2(b, b);
        }

        const float2* __restrict__ pc2 = (const float2*)(ws + OFF_VT  + (2*l)   * BATCH + jc * 128);
        const float2* __restrict__ pm2 = (const float2*)(ws + OFF_VT  + (2*l+1) * BATCH + jc * 128);
        const float2* __restrict__ pe2 = (const float2*)(ws + OFF_TCE + l       * BATCH + jc * 128);

        float s[8];
        #pragma unroll
        for (int k = 0; k < 8; ++k) s[k] = 0.0f;

        for (int jj = 0; jj < 64; jj += 4) {   // 4 j-pairs = 8 j per iter
            #pragma unroll
            for (int u = 0; u < 4; ++u) {
                float2 cc = pc2[jj + u];   // uniform -> scalar load
                float2 mm = pm2[jj + u];   // uniform -> scalar load
                float2 ee = pe2[jj + u];   // uniform -> scalar load
                #pragma unroll
                for (int k = 0; k < 8; ++k) {
                    float2 t0 = pk_fma(n2b[k], mm, ee);
                    float2 t1 = pk_fma(z2b[k], cc, t0);
                    s[k] += EXP2F(t1.x);
                    s[k] += EXP2F(t1.y);
                }
            }
        }

        __hip_bfloat16* pp = (__hip_bfloat16*)(ws + OFF_PP);
        size_t base = ((size_t)(jc * 64 + l)) * BATCH;
        #pragma unroll
        for (int k = 0; k < 8; ++k)
            pp[base + t + 256*k] = __float2bfloat16(s[k]);
    } else {
        // row path: 8 i per block, 4 j per thread over a j-half.
        // Packed over i-pairs: u-pairs are contiguous (natural float2 via
        // uniform s_load); v0.c/v1.c broadcast once per l (8 movs), then
        // 32 pk_fma replace 64 scalar fma per l.
        int bx2 = bx - DIMB;
        int ib8 = bx2 >> 1, ph = bx2 & 1;
        int i0 = ib8 * 8;
        int jb = ph * 1024 + 4 * t;
        int lane = t & 63, w = t >> 6;

        const float* __restrict__ Vt = ws + OFF_VT;
        const float* __restrict__ Up = ws + OFF_UP;

        float2 acc2[4][4];   // [i-pair][c]; .x = i=2p, .y = i=2p+1
        #pragma unroll
        for (int p = 0; p < 4; ++p)
            #pragma unroll
            for (int c = 0; c < 4; ++c)
                acc2[p][c] = make_float2(0.0f, 0.0f);

        for (int l = 0; l < LATENT; ++l) {
            float4 v0 = *(const float4*)(Vt + (2*l)   * BATCH + jb);
            float4 v1 = *(const float4*)(Vt + (2*l+1) * BATCH + jb);
            const float2* __restrict__ u0 = (const float2*)(Up + (2*l)   * BATCH + i0);  // uniform
            const float2* __restrict__ u1 = (const float2*)(Up + (2*l+1) * BATCH + i0);  // uniform
            float2 vb0[4] = { make_float2(v0.x, v0.x), make_float2(v0.y, v0.y),
                              make_float2(v0.z, v0.z), make_float2(v0.w, v0.w) };
            float2 vb1[4] = { make_float2(v1.x, v1.x), make_float2(v1.y, v1.y),
                              make_float2(v1.z, v1.z), make_float2(v1.w, v1.w) };
            #pragma unroll
            for (int p = 0; p < 4; ++p) {
                float2 a = u0[p], b = u1[p];
                #pragma unroll
                for (int c = 0; c < 4; ++c)
                    acc2[p][c] = pk_fma(a, vb0[c], pk_fma(b, vb1[c], acc2[p][c]));
            }
        }

        float4 ce4 = *(const float4*)(ws + OFF_CE + jb);
        #pragma unroll
        for (int i = 0; i < 8; ++i) {
            int p = i >> 1;
            float rc0 = ((i & 1) ? acc2[p][0].y : acc2[p][0].x) + ce4.x;
            float rc1 = ((i & 1) ? acc2[p][1].y : acc2[p][1].x) + ce4.y;
            float rc2 = ((i & 1) ? acc2[p][2].y : acc2[p][2].x) + ce4.z;
            float rc3 = ((i & 1) ? acc2[p][3].y : acc2[p][3].x) + ce4.w;
            float M = fmaxf(fmaxf(rc0, rc1), fmaxf(rc2, rc3));
            float S = EXP2F(rc0 - M) + EXP2F(rc1 - M)
                    + EXP2F(rc2 - M) + EXP2F(rc3 - M);
            #pragma unroll
            for (int off = 32; off > 0; off >>= 1) {
                float Mo = __shfl_xor(M, off, 64);
                float So = __shfl_xor(S, off, 64);
                float mn = fmaxf(M, Mo);
                S = S * EXP2F(M - mn) + So * EXP2F(Mo - mn);
                M = mn;
            }
            if (lane == 0) { RMs[i][w] = M; RSs[i][w] = S; }
        }
        __syncthreads();
        if (t < 8) {
            float M = RMs[t][0], S = RSs[t][0];
            #pragma unroll
            for (int w2 = 1; w2 < 4; ++w2) {
                float Mo = RMs[t][w2], So = RSs[t][w2];
                float mn = fmaxf(M, Mo);
                S = S * EXP2F(M - mn) + So * EXP2F(Mo - mn);
                M = mn;
            }
            ws[OFF_RMP + ph * BATCH + i0 + t] = M;
            ws[OFF_RSP + ph * BATCH + i0 + t] = S;
        }
    }
}

// Finalize (R7-proven 128-block form; R8's 512-block variant cost ~18 us via
// 4x same-cacheline device-scope atomics): tc = sum_i lqz_i - sum log2(PP-sum).
__global__ __launch_bounds__(256) void finalize_kernel(float* __restrict__ ws,
                                                       float* __restrict__ out) {
    __shared__ float s_tc[256];
    __shared__ float s_kl[256];
    int t = threadIdx.x;
    int gid = blockIdx.x * 256 + t;

    const __hip_bfloat16* __restrict__ pp = (const __hip_bfloat16*)(ws + OFF_PP);

    float acc = 0.0f, kl = 0.0f;
    #pragma unroll
    for (int k = 0; k < 4; ++k) {
        int f = gid + 32768 * k;          // 0..131071
        int l = f >> 11, i = f & 2047;
        float s = 0.0f;
        #pragma unroll
        for (int c = 0; c < 16; ++c)
            s += __bfloat162float(pp[((size_t)(c * 64 + l)) * BATCH + i]);
        acc -= LOG2F(s);                  // log2 domain; LN2-scaled at the end
    }

    if (gid < BATCH) {
        int i = gid;
        float M0 = ws[OFF_RMP + i], M1 = ws[OFF_RMP + BATCH + i];
        float S0 = ws[OFF_RSP + i], S1 = ws[OFF_RSP + BATCH + i];
        float mn = fmaxf(M0, M1);
        acc += mn + LOG2F(S0 * EXP2F(M0 - mn) + S1 * EXP2F(M1 - mn));
        kl = ws[OFF_KLP + i];
    }

    s_tc[t] = acc; s_kl[t] = kl;
    __syncthreads();
    for (int s2 = 128; s2 > 0; s2 >>= 1) {
        if (t < s2) { s_tc[t] += s_tc[t + s2]; s_kl[t] += s_kl[t + s2]; }
        __syncthreads();
    }
    if (t == 0) {
        atomicAdd(&ws[OFF_PART + 0], s_tc[0]);
        atomicAdd(&ws[OFF_PART + 1], s_kl[0]);
        __threadfence();
        unsigned int old = atomicAdd((unsigned int*)(ws + OFF_PART + 2), 1u);
        if (old == 127u) {
            float tc  = atomicAdd(&ws[OFF_PART + 0], 0.0f);
            float kl2 = atomicAdd(&ws[OFF_PART + 1], 0.0f);
            out[0] = BETA_M1 * (LN2 * tc / (float)BATCH) + 0.5f * (kl2 / (float)BATCH);
        }
    }
}

extern "C" void kernel_launch(void* const* d_in, const int* in_sizes, int n_in,
                              void* d_out, int out_size, void* d_ws, size_t ws_size,
                              hipStream_t stream) {
    const float* z        = (const float*)d_in[0];
    const float* z_mean   = (const float*)d_in[1];
    const float* z_logvar = (const float*)d_in[2];
    float* out = (float*)d_out;
    float* ws  = (float*)d_ws;

    precompute_kernel<<<128, 256, 0, stream>>>(z, z_mean, z_logvar, ws);
    main_kernel<<<DIMB + ROWB, 256, 0, stream>>>(ws);
    finalize_kernel<<<128, 256, 0, stream>>>(ws, out);
}

// Round 10
// 115.096 us; speedup vs baseline: 1.1273x; 1.1095x over previous
//
#include <hip/hip_runtime.h>
#include <hip/hip_bf16.h>
#include <math.h>

#define BATCH 2048
#define LATENT 64
#define LOG_2PI 1.8378770664093453f
#define BETA_M1 5.0f
#define LN2 0.69314718055994530942f
// C2 = -0.5 * log2(e)
#define C2 (-0.72134752044448170368f)
#define EXP2F __builtin_amdgcn_exp2f
#define LOG2F __builtin_amdgcn_logf

// packed fp32 fma: d.{x,y} = a.{x,y}*b.{x,y} + c.{x,y}  (one VOP3P inst)
__device__ __forceinline__ float2 pk_fma(float2 a, float2 b, float2 c) {
    float2 d;
    asm("v_pk_fma_f32 %0, %1, %2, %3" : "=v"(d) : "v"(a), "v"(b), "v"(c));
    return d;
}

// ws layout (float offsets):
//   Vt   [128][2048]  Vt[2l][j]=C2*inv, Vt[2l+1][j]=C2*m*inv
//   Tce  [64][2048]   Tce[l][j]=C2*(m^2*inv+lv+LOG2PI)
//   Up   [128][2048]  Up[2l][i]=z^2, Up[2l+1][i]=-2z
//   CE   [2048], KLP [2048]
//   RMP/RSP [2][2048] row-LSE partials (log2 domain)
//   PART [16]         PART[0]=tc, PART[1]=kl, PART[2]=ticket
//   PP   bf16 [16][64][2048] per-j-chunk raw exp sums (4 MB)
#define OFF_VT   0
#define OFF_TCE  (128*BATCH)
#define OFF_UP   (OFF_TCE + 64*BATCH)
#define OFF_CE   (OFF_UP + 128*BATCH)
#define OFF_KLP  (OFF_CE + BATCH)
#define OFF_RMP  (OFF_KLP + BATCH)
#define OFF_RSP  (OFF_RMP + 2*BATCH)
#define OFF_PART (OFF_RSP + 2*BATCH)
#define OFF_PP   (OFF_PART + 16)

// Precompute: grid 128 x 256, each block transposes 16 j x 64 l. (R0-proven.)
__global__ __launch_bounds__(256) void precompute_kernel(const float* __restrict__ z,
                                                         const float* __restrict__ zm,
                                                         const float* __restrict__ zlv,
                                                         float* __restrict__ ws) {
    __shared__ float Tz[16][65], Tm[16][65], Tlv[16][65];
    __shared__ float CEp[16][16], KLp[16][16];
    int t = threadIdx.x, lane = t & 63, w = t >> 6;
    int j0 = blockIdx.x * 16;

    #pragma unroll
    for (int p = 0; p < 4; ++p) {
        int jr = p * 4 + w;
        int idx = (j0 + jr) * LATENT + lane;
        Tz[jr][lane]  = z[idx];
        Tm[jr][lane]  = zm[idx];
        Tlv[jr][lane] = zlv[idx];
    }
    if (blockIdx.x == 0 && t < 16) ws[OFF_PART + t] = 0.0f;
    __syncthreads();

    int jl = t & 15, lg = t >> 4;
    int j = j0 + jl;
    float ce_acc = 0.0f, kl_acc = 0.0f;
    #pragma unroll
    for (int q = 0; q < 4; ++q) {
        int l = q * 16 + lg;
        float zv = Tz[jl][l];
        float m  = Tm[jl][l];
        float lv = Tlv[jl][l];
        float iv  = __expf(-lv);
        float civ = C2 * iv;
        float miv = m * iv;
        float cmv = C2 * miv;
        float cev = C2 * fmaf(m, miv, lv + LOG_2PI);
        ws[OFF_VT  + (2*l)   * BATCH + j] = civ;
        ws[OFF_VT  + (2*l+1) * BATCH + j] = cmv;
        ws[OFF_TCE + l       * BATCH + j] = cev;
        ws[OFF_UP  + (2*l)   * BATCH + j] = zv * zv;
        ws[OFF_UP  + (2*l+1) * BATCH + j] = -2.0f * zv;
        ce_acc += cev;
        kl_acc += fmaf(m, m, __expf(lv)) - lv - 1.0f;
    }
    CEp[lg][jl] = ce_acc;
    KLp[lg][jl] = kl_acc;
    __syncthreads();
    if (t < 16) {
        float ce = 0.0f, kl = 0.0f;
        #pragma unroll
        for (int g = 0; g < 16; ++g) { ce += CEp[g][t]; kl += KLp[g][t]; }
        ws[OFF_CE  + j0 + t] = ce;
        ws[OFF_KLP + j0 + t] = kl;
    }
}

// Fused main: blocks [0,1024) dim path (8 i/thread, all 2048 i, 128-j chunk,
//             pk_fma over j-pairs -- R8-proven, main 53.2 us),
//             blocks [1024,1536) row path (scalar fma, float4 -- R0/R7-proven;
//             R9's packed-row experiment demoted s_loads and cost +14 us).
#define DIMB 1024
#define ROWB 512
__global__ __launch_bounds__(256) void main_kernel(float* __restrict__ ws) {
    __shared__ float RMs[8][4], RSs[8][4];
    int bx = blockIdx.x, t = threadIdx.x;

    if (bx < DIMB) {
        int l  = bx >> 4;
        int jc = bx & 15;

        const float* __restrict__ up0 = ws + OFF_UP + (2*l)   * BATCH;
        const float* __restrict__ up1 = ws + OFF_UP + (2*l+1) * BATCH;
        float2 z2b[8], n2b[8];
        #pragma unroll
        for (int k = 0; k < 8; ++k) {
            float a = up0[t + 256*k];
            float b = up1[t + 256*k];
            z2b[k] = make_float2(a, a);
            n2b[k] = make_float2(b, b);
        }

        const float2* __restrict__ pc2 = (const float2*)(ws + OFF_VT  + (2*l)   * BATCH + jc * 128);
        const float2* __restrict__ pm2 = (const float2*)(ws + OFF_VT  + (2*l+1) * BATCH + jc * 128);
        const float2* __restrict__ pe2 = (const float2*)(ws + OFF_TCE + l       * BATCH + jc * 128);

        float s[8];
        #pragma unroll
        for (int k = 0; k < 8; ++k) s[k] = 0.0f;

        for (int jj = 0; jj < 64; jj += 4) {   // 4 j-pairs = 8 j per iter
            #pragma unroll
            for (int u = 0; u < 4; ++u) {
                float2 cc = pc2[jj + u];   // uniform -> scalar load
                float2 mm = pm2[jj + u];   // uniform -> scalar load
                float2 ee = pe2[jj + u];   // uniform -> scalar load
                #pragma unroll
                for (int k = 0; k < 8; ++k) {
                    float2 t0 = pk_fma(n2b[k], mm, ee);
                    float2 t1 = pk_fma(z2b[k], cc, t0);
                    s[k] += EXP2F(t1.x);
                    s[k] += EXP2F(t1.y);
                }
            }
        }

        __hip_bfloat16* pp = (__hip_bfloat16*)(ws + OFF_PP);
        size_t base = ((size_t)(jc * 64 + l)) * BATCH;
        #pragma unroll
        for (int k = 0; k < 8; ++k)
            pp[base + t + 256*k] = __float2bfloat16(s[k]);
    } else {
        // row path: 8 i per block, 4 j per thread over a j-half (R0-proven)
        int bx2 = bx - DIMB;
        int ib8 = bx2 >> 1, ph = bx2 & 1;
        int i0 = ib8 * 8;
        int jb = ph * 1024 + 4 * t;
        int lane = t & 63, w = t >> 6;

        const float* __restrict__ Vt = ws + OFF_VT;
        const float* __restrict__ Up = ws + OFF_UP;

        float r[8][4];
        #pragma unroll
        for (int i = 0; i < 8; ++i)
            r[i][0] = r[i][1] = r[i][2] = r[i][3] = 0.0f;

        for (int l = 0; l < LATENT; ++l) {
            float4 v0 = *(const float4*)(Vt + (2*l)   * BATCH + jb);
            float4 v1 = *(const float4*)(Vt + (2*l+1) * BATCH + jb);
            const float* __restrict__ u0 = Up + (2*l)   * BATCH + i0;  // uniform -> s_load
            const float* __restrict__ u1 = Up + (2*l+1) * BATCH + i0;  // uniform -> s_load
            #pragma unroll
            for (int i = 0; i < 8; ++i) {
                float a = u0[i], b = u1[i];
                r[i][0] = fmaf(a, v0.x, fmaf(b, v1.x, r[i][0]));
                r[i][1] = fmaf(a, v0.y, fmaf(b, v1.y, r[i][1]));
                r[i][2] = fmaf(a, v0.z, fmaf(b, v1.z, r[i][2]));
                r[i][3] = fmaf(a, v0.w, fmaf(b, v1.w, r[i][3]));
            }
        }

        float4 ce4 = *(const float4*)(ws + OFF_CE + jb);
        #pragma unroll
        for (int i = 0; i < 8; ++i) {
            float rc0 = r[i][0] + ce4.x, rc1 = r[i][1] + ce4.y;
            float rc2 = r[i][2] + ce4.z, rc3 = r[i][3] + ce4.w;
            float M = fmaxf(fmaxf(rc0, rc1), fmaxf(rc2, rc3));
            float S = EXP2F(rc0 - M) + EXP2F(rc1 - M)
                    + EXP2F(rc2 - M) + EXP2F(rc3 - M);
            #pragma unroll
            for (int off = 32; off > 0; off >>= 1) {
                float Mo = __shfl_xor(M, off, 64);
                float So = __shfl_xor(S, off, 64);
                float mn = fmaxf(M, Mo);
                S = S * EXP2F(M - mn) + So * EXP2F(Mo - mn);
                M = mn;
            }
            if (lane == 0) { RMs[i][w] = M; RSs[i][w] = S; }
        }
        __syncthreads();
        if (t < 8) {
            float M = RMs[t][0], S = RSs[t][0];
            #pragma unroll
            for (int w2 = 1; w2 < 4; ++w2) {
                float Mo = RMs[t][w2], So = RSs[t][w2];
                float mn = fmaxf(M, Mo);
                S = S * EXP2F(M - mn) + So * EXP2F(Mo - mn);
                M = mn;
            }
            ws[OFF_RMP + ph * BATCH + i0 + t] = M;
            ws[OFF_RSP + ph * BATCH + i0 + t] = S;
        }
    }
}

// Finalize (R7-proven 128-block form): tc = sum_i lqz_i - sum log2(PP-sum).
// Last block (atomic ticket) assembles the scalar output.
__global__ __launch_bounds__(256) void finalize_kernel(float* __restrict__ ws,
                                                       float* __restrict__ out) {
    __shared__ float s_tc[256];
    __shared__ float s_kl[256];
    int t = threadIdx.x;
    int gid = blockIdx.x * 256 + t;

    const __hip_bfloat16* __restrict__ pp = (const __hip_bfloat16*)(ws + OFF_PP);

    float acc = 0.0f, kl = 0.0f;
    #pragma unroll
    for (int k = 0; k < 4; ++k) {
        int f = gid + 32768 * k;          // 0..131071
        int l = f >> 11, i = f & 2047;
        float s = 0.0f;
        #pragma unroll
        for (int c = 0; c < 16; ++c)
            s += __bfloat162float(pp[((size_t)(c * 64 + l)) * BATCH + i]);
        acc -= LOG2F(s);                  // log2 domain; LN2-scaled at the end
    }

    if (gid < BATCH) {
        int i = gid;
        float M0 = ws[OFF_RMP + i], M1 = ws[OFF_RMP + BATCH + i];
        float S0 = ws[OFF_RSP + i], S1 = ws[OFF_RSP + BATCH + i];
        float mn = fmaxf(M0, M1);
        acc += mn + LOG2F(S0 * EXP2F(M0 - mn) + S1 * EXP2F(M1 - mn));
        kl = ws[OFF_KLP + i];
    }

    s_tc[t] = acc; s_kl[t] = kl;
    __syncthreads();
    for (int s2 = 128; s2 > 0; s2 >>= 1) {
        if (t < s2) { s_tc[t] += s_tc[t + s2]; s_kl[t] += s_kl[t + s2]; }
        __syncthreads();
    }
    if (t == 0) {
        atomicAdd(&ws[OFF_PART + 0], s_tc[0]);
        atomicAdd(&ws[OFF_PART + 1], s_kl[0]);
        __threadfence();
        unsigned int old = atomicAdd((unsigned int*)(ws + OFF_PART + 2), 1u);
        if (old == 127u) {
            float tc  = atomicAdd(&ws[OFF_PART + 0], 0.0f);
            float kl2 = atomicAdd(&ws[OFF_PART + 1], 0.0f);
            out[0] = BETA_M1 * (LN2 * tc / (float)BATCH) + 0.5f * (kl2 / (float)BATCH);
        }
    }
}

extern "C" void kernel_launch(void* const* d_in, const int* in_sizes, int n_in,
                              void* d_out, int out_size, void* d_ws, size_t ws_size,
                              hipStream_t stream) {
    const float* z        = (const float*)d_in[0];
    const float* z_mean   = (const float*)d_in[1];
    const float* z_logvar = (const float*)d_in[2];
    float* out = (float*)d_out;
    float* ws  = (float*)d_ws;

    precompute_kernel<<<128, 256, 0, stream>>>(z, z_mean, z_logvar, ws);
    main_kernel<<<DIMB + ROWB, 256, 0, stream>>>(ws);
    finalize_kernel<<<128, 256, 0, stream>>>(ws, out);
}